// Round 1
// baseline (1917.046 us; speedup 1.0000x reference)
//
#include <hip/hip_runtime.h>
#include <hip/hip_bf16.h>
#include <math.h>

#define NN 150000
#define EE 600000
#define GG 5000
#define NI 16
#define EI 8
#define GFD 32
#define HH 64
#define CC 40

#define TILE_E 16
#define KC 4
#define NCHUNK 16
#define WPAD 68

// ---------------- K1: fused edge MLP + bilinear message + scatter ----------------
__global__ __launch_bounds__(256) void k1_edge(
    const float* __restrict__ x, const int* __restrict__ ei,
    const float* __restrict__ ea,
    const float* __restrict__ W_e1, const float* __restrict__ b_e1,
    const float* __restrict__ W_e2, const float* __restrict__ b_e2,
    float* __restrict__ agg, float* __restrict__ cnt)
{
    __shared__ float sEH[TILE_E][64];                 // relu(ea@W_e1+b_e1)
    __shared__ float sXS[TILE_E][16];                 // gathered x[src]
    __shared__ __align__(16) float sW[KC * 16 * WPAD]; // W_e2 chunk, [kp][i][h] padded
    __shared__ int sDst[TILE_E];

    const int t = threadIdx.x;
    const int eb = blockIdx.x * TILE_E;

    // gather x[src] and dst
    {
        int e = t >> 4, i = t & 15;
        int src = ei[eb + e];
        sXS[e][i] = x[(size_t)src * NI + i];
        if (t < TILE_E) sDst[t] = ei[EE + eb + t];
    }
    // edge MLP layer 1: 16 edges x 64
    #pragma unroll
    for (int r = 0; r < 4; ++r) {
        int idx = t + r * 256;
        int e = idx >> 6, k = idx & 63;
        const float* eap = ea + (size_t)(eb + e) * EI;
        float v = b_e1[k];
        #pragma unroll
        for (int j = 0; j < EI; ++j) v += eap[j] * W_e1[j * 64 + k];
        sEH[e][k] = fmaxf(v, 0.f);
    }
    __syncthreads();

    const int h  = t & 63;
    const int eg = t >> 6;    // 0..3, each owns 4 edges

    float xs[4][16];
    #pragma unroll
    for (int e2 = 0; e2 < 4; ++e2)
        #pragma unroll
        for (int i = 0; i < 16; ++i)
            xs[e2][i] = sXS[eg * 4 + e2][i];

    // init accumulators with b_e2 bias term: sum_i xs[i]*b_e2[i*64+h]
    float acc[4] = {0.f, 0.f, 0.f, 0.f};
    #pragma unroll
    for (int i = 0; i < 16; ++i) {
        float b = b_e2[i * 64 + h];
        #pragma unroll
        for (int e2 = 0; e2 < 4; ++e2) acc[e2] += xs[e2][i] * b;
    }

    for (int kc = 0; kc < NCHUNK; ++kc) {
        // stage 4 rows of W_e2, transposed [kp][i][h] with pad 68
        const float* w2base = W_e2 + (size_t)kc * KC * 1024;
        #pragma unroll
        for (int q = 0; q < 4; ++q) {
            int f = t * 16 + q * 4;            // 0..4095
            float4 v = *(const float4*)(w2base + f);
            int kp = f >> 10, rem = f & 1023;
            int i = rem >> 6, hh = rem & 63;
            *(float4*)&sW[kp * (16 * WPAD) + i * WPAD + hh] = v;
        }
        __syncthreads();

        float ehr[4][4];
        #pragma unroll
        for (int e2 = 0; e2 < 4; ++e2) {
            float4 v = *(const float4*)&sEH[eg * 4 + e2][kc * 4];
            ehr[e2][0] = v.x; ehr[e2][1] = v.y; ehr[e2][2] = v.z; ehr[e2][3] = v.w;
        }
        #pragma unroll
        for (int kp = 0; kp < KC; ++kp) {
            float w[16];
            #pragma unroll
            for (int i = 0; i < 16; ++i) w[i] = sW[kp * (16 * WPAD) + i * WPAD + h];
            #pragma unroll
            for (int e2 = 0; e2 < 4; ++e2) {
                float u = 0.f;
                #pragma unroll
                for (int i = 0; i < 16; ++i) u += xs[e2][i] * w[i];
                acc[e2] += ehr[e2][kp] * u;
            }
        }
        __syncthreads();
    }

    #pragma unroll
    for (int e2 = 0; e2 < 4; ++e2) {
        int d = sDst[eg * 4 + e2];
        atomicAdd(&agg[(size_t)d * 64 + h], acc[e2]);
    }
    if (t < TILE_E) atomicAdd(&cnt[sDst[t]], 1.0f);
}

// ---------------- K2: mean + root + relu (in place over agg) + gate ----------------
__global__ __launch_bounds__(256) void k2_node(
    const float* __restrict__ x, const float* __restrict__ root,
    const float* __restrict__ conv_bias, const float* __restrict__ cnt,
    float* __restrict__ hn,
    const float* __restrict__ Wg, const float* __restrict__ bg,
    float* __restrict__ gate)
{
    int t = threadIdx.x;
    int n = blockIdx.x * 4 + (t >> 6);
    int h = t & 63;
    float inv = 1.0f / fmaxf(cnt[n], 1.0f);
    float v = hn[(size_t)n * 64 + h] * inv + conv_bias[h];
    const float* xp = x + (size_t)n * NI;
    #pragma unroll
    for (int i = 0; i < NI; ++i) v += xp[i] * root[i * 64 + h];
    v = fmaxf(v, 0.f);
    hn[(size_t)n * 64 + h] = v;
    float gv = v * Wg[h];
    #pragma unroll
    for (int off = 32; off; off >>= 1) gv += __shfl_xor(gv, off);
    if (h == 0) gate[n] = gv + bg[0];
}

// ---------------- K3a: segment max of gate (monotone uint map) ----------------
__global__ void k3a_max(const float* __restrict__ gate, const int* __restrict__ batch,
                        unsigned* __restrict__ gmax)
{
    int n = blockIdx.x * 256 + threadIdx.x;
    if (n >= NN) return;
    unsigned b = __float_as_uint(gate[n]);
    unsigned m = (b & 0x80000000u) ? ~b : (b | 0x80000000u);
    atomicMax(&gmax[batch[n]], m);
}

// ---------------- K3b: accumulate exp-weighted context + denom ----------------
__global__ __launch_bounds__(256) void k3b_acc(
    const float* __restrict__ gate, const int* __restrict__ batch,
    const float* __restrict__ hn, const unsigned* __restrict__ gmax,
    float* __restrict__ denom, float* __restrict__ gctx)
{
    int t = threadIdx.x;
    int n = blockIdx.x * 4 + (t >> 6);
    int h = t & 63;
    int g = batch[n];
    unsigned mb = gmax[g];
    float m = (mb & 0x80000000u) ? __uint_as_float(mb ^ 0x80000000u)
                                 : __uint_as_float(~mb);
    float e = expf(gate[n] - m);
    atomicAdd(&gctx[(size_t)g * 64 + h], e * hn[(size_t)n * 64 + h]);
    if (h == 0) atomicAdd(&denom[g], e);
}

// ---------------- K3c: normalize context ----------------
__global__ void k3c_norm(float* __restrict__ gctx, const float* __restrict__ denom)
{
    int i = blockIdx.x * 256 + threadIdx.x;  // < G*64
    float d = denom[i >> 6];
    gctx[i] = d > 0.f ? gctx[i] / d : 0.f;
}

// ---------------- K4: FC head + log_softmax + stop ----------------
__global__ __launch_bounds__(256) void k4_out(
    const float* __restrict__ hn, const float* __restrict__ gctx,
    const int* __restrict__ batch, const float* __restrict__ pocket,
    const float* __restrict__ W_fc1, const float* __restrict__ b_fc1,
    const float* __restrict__ W_np, const float* __restrict__ b_np,
    const float* __restrict__ W_sp, const float* __restrict__ b_sp,
    float* __restrict__ out_np, float* __restrict__ out_stop)
{
    __shared__ float sF[4][160];
    __shared__ float sf2[4][64];
    int t = threadIdx.x;
    int nd = t >> 6;
    int h = t & 63;
    int n = blockIdx.x * 4 + nd;
    int g = batch[n];
    float hv = hn[(size_t)n * 64 + h];
    float gc = gctx[(size_t)g * 64 + h];
    sF[nd][h] = hv;
    sF[nd][64 + h] = gc;
    if (h < GFD) sF[nd][128 + h] = pocket[(size_t)g * GFD + h];
    __syncthreads();

    float f = b_fc1[h];
    #pragma unroll 8
    for (int j = 0; j < 160; ++j) f += sF[nd][j] * W_fc1[j * 64 + h];
    f = fmaxf(f, 0.f);
    sf2[nd][h] = f;

    // stop head: sigmoid(gc . W_sp + b_sp)
    float sv = gc * W_sp[h];
    #pragma unroll
    for (int off = 32; off; off >>= 1) sv += __shfl_xor(sv, off);
    __syncthreads();

    float logit = -INFINITY;
    if (h < CC) {
        logit = b_np[h];
        #pragma unroll 8
        for (int k = 0; k < 64; ++k) logit += sf2[nd][k] * W_np[k * CC + h];
    }
    float mx = logit;
    #pragma unroll
    for (int off = 32; off; off >>= 1) mx = fmaxf(mx, __shfl_xor(mx, off));
    float ex = (h < CC) ? expf(logit - mx) : 0.f;
    float s = ex;
    #pragma unroll
    for (int off = 32; off; off >>= 1) s += __shfl_xor(s, off);
    if (h < CC) out_np[(size_t)n * CC + h] = logit - mx - logf(s);
    if (h == 0) out_stop[n] = 1.f / (1.f + expf(-(sv + b_sp[0])));
}

extern "C" void kernel_launch(void* const* d_in, const int* in_sizes, int n_in,
                              void* d_out, int out_size, void* d_ws, size_t ws_size,
                              hipStream_t stream)
{
    (void)in_sizes; (void)n_in; (void)out_size; (void)ws_size;
    const float* x        = (const float*)d_in[0];
    const int*   ei       = (const int*)d_in[1];
    const float* ea       = (const float*)d_in[2];
    const int*   batch    = (const int*)d_in[3];
    const float* pocket   = (const float*)d_in[4];
    const float* W_e1     = (const float*)d_in[5];
    const float* b_e1     = (const float*)d_in[6];
    const float* W_e2     = (const float*)d_in[7];
    const float* b_e2     = (const float*)d_in[8];
    const float* root     = (const float*)d_in[9];
    const float* conv_b   = (const float*)d_in[10];
    const float* Wg       = (const float*)d_in[11];
    const float* bg       = (const float*)d_in[12];
    const float* W_fc1    = (const float*)d_in[13];
    const float* b_fc1    = (const float*)d_in[14];
    const float* W_np     = (const float*)d_in[15];
    const float* b_np     = (const float*)d_in[16];
    const float* W_sp     = (const float*)d_in[17];
    const float* b_sp     = (const float*)d_in[18];

    float* ws = (float*)d_ws;
    float*    agg   = ws;                         // N*64
    float*    cnt   = agg + (size_t)NN * 64;      // N
    float*    gate  = cnt + NN;                   // N
    unsigned* gmax  = (unsigned*)(gate + NN);     // G
    float*    denom = (float*)(gmax + GG);        // G
    float*    gctx  = denom + GG;                 // G*64

    hipMemsetAsync(agg, 0, ((size_t)NN * 64 + NN) * sizeof(float), stream);
    hipMemsetAsync(gmax, 0, ((size_t)2 * GG + (size_t)GG * 64) * sizeof(float), stream);

    k1_edge<<<EE / TILE_E, 256, 0, stream>>>(x, ei, ea, W_e1, b_e1, W_e2, b_e2, agg, cnt);
    k2_node<<<NN / 4, 256, 0, stream>>>(x, root, conv_b, cnt, agg, Wg, bg, gate);
    k3a_max<<<(NN + 255) / 256, 256, 0, stream>>>(gate, batch, gmax);
    k3b_acc<<<NN / 4, 256, 0, stream>>>(gate, batch, agg, gmax, denom, gctx);
    k3c_norm<<<GG * 64 / 256, 256, 0, stream>>>(gctx, denom);

    float* out_np   = (float*)d_out;
    float* out_stop = out_np + (size_t)NN * CC;
    k4_out<<<NN / 4, 256, 0, stream>>>(agg, gctx, batch, pocket,
                                       W_fc1, b_fc1, W_np, b_np, W_sp, b_sp,
                                       out_np, out_stop);
}

// Round 2
// 681.011 us; speedup vs baseline: 2.8150x; 2.8150x over previous
//
#include <hip/hip_runtime.h>
#include <hip/hip_bf16.h>
#include <math.h>

#define NN 150000
#define EE 600000
#define GG 5000
#define NI 16
#define EI 8
#define GFD 32
#define HH 64
#define CC 40

typedef __attribute__((ext_vector_type(8))) short short8v;
typedef __attribute__((ext_vector_type(16))) float f32x16;

__device__ __forceinline__ unsigned short f2bf(float f) {
    __hip_bfloat16 h = __float2bfloat16(f);
    return __builtin_bit_cast(unsigned short, h);
}
__device__ __forceinline__ float bf2f(unsigned short u) {
    return __uint_as_float(((unsigned)u) << 16);
}

// ---------------- K0: prep W2T bf16 [64][1040]: W2T[h][k*16+i]=W_e2[k][i*64+h], tail=b_e2 ----------------
__global__ void k0_prep(const float* __restrict__ W_e2, const float* __restrict__ b_e2,
                        unsigned short* __restrict__ W2T)
{
    int idx = blockIdx.x * 256 + threadIdx.x;
    if (idx >= 64 * 1040) return;
    int h = idx / 1040, j = idx % 1040;
    float v;
    if (j < 1024) { int k = j >> 4, i = j & 15; v = W_e2[k * 1024 + i * 64 + h]; }
    else          { int i = j - 1024;          v = b_e2[i * 64 + h]; }
    W2T[idx] = f2bf(v);
}

// ---------------- K1: fused edge MLP + MFMA z-GEMM + scatter ----------------
// Z[e, k*16+i] = eh[e,k]*xs[e,i];  msg = Z @ W2flat  (K=1024 + 16 bias rows)
__global__ __launch_bounds__(256) void k1_mfma(
    const float* __restrict__ x, const int* __restrict__ ei,
    const float* __restrict__ ea,
    const float* __restrict__ W_e1, const float* __restrict__ b_e1,
    const unsigned short* __restrict__ W2T,
    float* __restrict__ agg, float* __restrict__ cnt)
{
    __shared__ unsigned short sEHT[64][256];   // [k][e ^ ((k&31)<<1)]  bf16
    __shared__ float sXS[256][18];             // gathered x[src], f32
    __shared__ int sDst[256];

    const int t = threadIdx.x;
    const long long eb = (long long)blockIdx.x * 256;

    // ---- stage xs + dst + cnt ----
    {
        long long ge = eb + t;
        if (ge < EE) {
            int src = ei[ge];
            int d = ei[EE + ge];
            sDst[t] = d;
            const float2* xp = (const float2*)(x + (size_t)src * NI);
            #pragma unroll
            for (int q = 0; q < 8; ++q) *(float2*)&sXS[t][q * 2] = xp[q];
            atomicAdd(&cnt[d], 1.0f);
        } else {
            sDst[t] = -1;
            #pragma unroll
            for (int q = 0; q < 8; ++q) *(float2*)&sXS[t][q * 2] = make_float2(0.f, 0.f);
        }
    }
    // ---- edge MLP layer 1 -> sEHT (transposed, swizzled) ----
    {
        const int k = t & 63;
        const int w = t >> 6;
        float w1[8];
        float b1 = b_e1[k];
        #pragma unroll
        for (int j = 0; j < 8; ++j) w1[j] = W_e1[j * 64 + k];
        for (int r = 0; r < 64; ++r) {
            int e = w * 64 + r;
            long long ge = eb + e;
            float v = 0.f;
            if (ge < EE) {
                const float* eap = ea + ge * EI;
                v = b1;
                #pragma unroll
                for (int j = 0; j < 8; ++j) v = fmaf(eap[j], w1[j], v);
                v = fmaxf(v, 0.f);
            }
            sEHT[k][e ^ ((k & 31) << 1)] = f2bf(v);
        }
    }
    __syncthreads();

    // ---- MFMA main loop: wave-tile = 64 edges x 64 h ----
    const int lane = t & 63;
    const int w = t >> 6;
    const int mr = lane & 31;       // row-within-Mtile / col-within-Ntile
    const int half = lane >> 5;     // k-half selector
    const int mb = w * 64;          // wave's edge base within block

    float xs0[8], xs1[8];
    #pragma unroll
    for (int q = 0; q < 8; ++q) {
        xs0[q] = sXS[mb + mr][half * 8 + q];
        xs1[q] = sXS[mb + 32 + mr][half * 8 + q];
    }

    f32x16 acc00, acc01, acc10, acc11;
    #pragma unroll
    for (int r = 0; r < 16; ++r) { acc00[r] = 0.f; acc01[r] = 0.f; acc10[r] = 0.f; acc11[r] = 0.f; }

    const unsigned short* Bp0 = W2T + (size_t)mr * 1040 + half * 8;
    const unsigned short* Bp1 = W2T + (size_t)(32 + mr) * 1040 + half * 8;

    #pragma unroll 2
    for (int c = 0; c < 64; ++c) {
        short8v b0 = *(const short8v*)(Bp0 + c * 16);
        short8v b1 = *(const short8v*)(Bp1 + c * 16);
        int cc = (c & 31) << 1;
        float eh0 = bf2f(sEHT[c][(mb + mr) ^ cc]);
        float eh1 = bf2f(sEHT[c][(mb + 32 + mr) ^ cc]);
        short8v a0, a1;
        #pragma unroll
        for (int q = 0; q < 8; ++q) {
            a0[q] = (short)f2bf(eh0 * xs0[q]);
            a1[q] = (short)f2bf(eh1 * xs1[q]);
        }
        acc00 = __builtin_amdgcn_mfma_f32_32x32x16_bf16(a0, b0, acc00, 0, 0, 0);
        acc01 = __builtin_amdgcn_mfma_f32_32x32x16_bf16(a0, b1, acc01, 0, 0, 0);
        acc10 = __builtin_amdgcn_mfma_f32_32x32x16_bf16(a1, b0, acc10, 0, 0, 0);
        acc11 = __builtin_amdgcn_mfma_f32_32x32x16_bf16(a1, b1, acc11, 0, 0, 0);
    }
    // bias chunk: eh = 1, B rows = b_e2 (j = 1024..1039)
    {
        short8v b0 = *(const short8v*)(Bp0 + 1024);
        short8v b1 = *(const short8v*)(Bp1 + 1024);
        short8v a0, a1;
        #pragma unroll
        for (int q = 0; q < 8; ++q) {
            a0[q] = (short)f2bf(xs0[q]);
            a1[q] = (short)f2bf(xs1[q]);
        }
        acc00 = __builtin_amdgcn_mfma_f32_32x32x16_bf16(a0, b0, acc00, 0, 0, 0);
        acc01 = __builtin_amdgcn_mfma_f32_32x32x16_bf16(a0, b1, acc01, 0, 0, 0);
        acc10 = __builtin_amdgcn_mfma_f32_32x32x16_bf16(a1, b0, acc10, 0, 0, 0);
        acc11 = __builtin_amdgcn_mfma_f32_32x32x16_bf16(a1, b1, acc11, 0, 0, 0);
    }

    // ---- epilogue: scatter via atomics (C layout: col=lane&31, row=(r&3)+8*(r>>2)+4*half) ----
    #pragma unroll
    for (int r = 0; r < 16; ++r) {
        int row = (r & 3) + 8 * (r >> 2) + 4 * half;
        int m0 = mb + row;
        int m1 = mb + 32 + row;
        int d0 = sDst[m0];
        int d1 = sDst[m1];
        if (d0 >= 0) {
            atomicAdd(&agg[(size_t)d0 * 64 + mr],      acc00[r]);
            atomicAdd(&agg[(size_t)d0 * 64 + 32 + mr], acc01[r]);
        }
        if (d1 >= 0) {
            atomicAdd(&agg[(size_t)d1 * 64 + mr],      acc10[r]);
            atomicAdd(&agg[(size_t)d1 * 64 + 32 + mr], acc11[r]);
        }
    }
}

// ---------------- K2: mean + root + relu (in place over agg) + gate ----------------
__global__ __launch_bounds__(256) void k2_node(
    const float* __restrict__ x, const float* __restrict__ root,
    const float* __restrict__ conv_bias, const float* __restrict__ cnt,
    float* __restrict__ hn,
    const float* __restrict__ Wg, const float* __restrict__ bg,
    float* __restrict__ gate)
{
    int t = threadIdx.x;
    int n = blockIdx.x * 4 + (t >> 6);
    int h = t & 63;
    float inv = 1.0f / fmaxf(cnt[n], 1.0f);
    float v = hn[(size_t)n * 64 + h] * inv + conv_bias[h];
    const float* xp = x + (size_t)n * NI;
    #pragma unroll
    for (int i = 0; i < NI; ++i) v += xp[i] * root[i * 64 + h];
    v = fmaxf(v, 0.f);
    hn[(size_t)n * 64 + h] = v;
    float gv = v * Wg[h];
    #pragma unroll
    for (int off = 32; off; off >>= 1) gv += __shfl_xor(gv, off);
    if (h == 0) gate[n] = gv + bg[0];
}

// ---------------- K3a: segment max of gate (monotone uint map) ----------------
__global__ void k3a_max(const float* __restrict__ gate, const int* __restrict__ batch,
                        unsigned* __restrict__ gmax)
{
    int n = blockIdx.x * 256 + threadIdx.x;
    if (n >= NN) return;
    unsigned b = __float_as_uint(gate[n]);
    unsigned m = (b & 0x80000000u) ? ~b : (b | 0x80000000u);
    atomicMax(&gmax[batch[n]], m);
}

// ---------------- K3b: accumulate exp-weighted context + denom ----------------
__global__ __launch_bounds__(256) void k3b_acc(
    const float* __restrict__ gate, const int* __restrict__ batch,
    const float* __restrict__ hn, const unsigned* __restrict__ gmax,
    float* __restrict__ denom, float* __restrict__ gctx)
{
    int t = threadIdx.x;
    int n = blockIdx.x * 4 + (t >> 6);
    int h = t & 63;
    int g = batch[n];
    unsigned mb = gmax[g];
    float m = (mb & 0x80000000u) ? __uint_as_float(mb ^ 0x80000000u)
                                 : __uint_as_float(~mb);
    float e = expf(gate[n] - m);
    atomicAdd(&gctx[(size_t)g * 64 + h], e * hn[(size_t)n * 64 + h]);
    if (h == 0) atomicAdd(&denom[g], e);
}

// ---------------- K3c: normalize context ----------------
__global__ void k3c_norm(float* __restrict__ gctx, const float* __restrict__ denom)
{
    int i = blockIdx.x * 256 + threadIdx.x;  // < G*64
    float d = denom[i >> 6];
    gctx[i] = d > 0.f ? gctx[i] / d : 0.f;
}

// ---------------- K4: FC head + log_softmax + stop ----------------
__global__ __launch_bounds__(256) void k4_out(
    const float* __restrict__ hn, const float* __restrict__ gctx,
    const int* __restrict__ batch, const float* __restrict__ pocket,
    const float* __restrict__ W_fc1, const float* __restrict__ b_fc1,
    const float* __restrict__ W_np, const float* __restrict__ b_np,
    const float* __restrict__ W_sp, const float* __restrict__ b_sp,
    float* __restrict__ out_np, float* __restrict__ out_stop)
{
    __shared__ float sF[4][160];
    __shared__ float sf2[4][64];
    int t = threadIdx.x;
    int nd = t >> 6;
    int h = t & 63;
    int n = blockIdx.x * 4 + nd;
    int g = batch[n];
    float hv = hn[(size_t)n * 64 + h];
    float gc = gctx[(size_t)g * 64 + h];
    sF[nd][h] = hv;
    sF[nd][64 + h] = gc;
    if (h < GFD) sF[nd][128 + h] = pocket[(size_t)g * GFD + h];
    __syncthreads();

    float f = b_fc1[h];
    #pragma unroll 8
    for (int j = 0; j < 160; ++j) f += sF[nd][j] * W_fc1[j * 64 + h];
    f = fmaxf(f, 0.f);
    sf2[nd][h] = f;

    float sv = gc * W_sp[h];
    #pragma unroll
    for (int off = 32; off; off >>= 1) sv += __shfl_xor(sv, off);
    __syncthreads();

    float logit = -INFINITY;
    if (h < CC) {
        logit = b_np[h];
        #pragma unroll 8
        for (int k = 0; k < 64; ++k) logit += sf2[nd][k] * W_np[k * CC + h];
    }
    float mx = logit;
    #pragma unroll
    for (int off = 32; off; off >>= 1) mx = fmaxf(mx, __shfl_xor(mx, off));
    float ex = (h < CC) ? expf(logit - mx) : 0.f;
    float s = ex;
    #pragma unroll
    for (int off = 32; off; off >>= 1) s += __shfl_xor(s, off);
    if (h < CC) out_np[(size_t)n * CC + h] = logit - mx - logf(s);
    if (h == 0) out_stop[n] = 1.f / (1.f + expf(-(sv + b_sp[0])));
}

extern "C" void kernel_launch(void* const* d_in, const int* in_sizes, int n_in,
                              void* d_out, int out_size, void* d_ws, size_t ws_size,
                              hipStream_t stream)
{
    (void)in_sizes; (void)n_in; (void)out_size; (void)ws_size;
    const float* x        = (const float*)d_in[0];
    const int*   ei       = (const int*)d_in[1];
    const float* ea       = (const float*)d_in[2];
    const int*   batch    = (const int*)d_in[3];
    const float* pocket   = (const float*)d_in[4];
    const float* W_e1     = (const float*)d_in[5];
    const float* b_e1     = (const float*)d_in[6];
    const float* W_e2     = (const float*)d_in[7];
    const float* b_e2     = (const float*)d_in[8];
    const float* root     = (const float*)d_in[9];
    const float* conv_b   = (const float*)d_in[10];
    const float* Wg       = (const float*)d_in[11];
    const float* bg       = (const float*)d_in[12];
    const float* W_fc1    = (const float*)d_in[13];
    const float* b_fc1    = (const float*)d_in[14];
    const float* W_np     = (const float*)d_in[15];
    const float* b_np     = (const float*)d_in[16];
    const float* W_sp     = (const float*)d_in[17];
    const float* b_sp     = (const float*)d_in[18];

    float* ws = (float*)d_ws;
    float*    agg   = ws;                         // N*64
    float*    cnt   = agg + (size_t)NN * 64;      // N
    float*    gate  = cnt + NN;                   // N
    unsigned* gmax  = (unsigned*)(gate + NN);     // G
    float*    denom = (float*)(gmax + GG);        // G
    float*    gctx  = denom + GG;                 // G*64
    unsigned short* W2T = (unsigned short*)(gctx + (size_t)GG * 64); // 64*1040 bf16

    hipMemsetAsync(agg, 0, ((size_t)NN * 64 + NN) * sizeof(float), stream);
    hipMemsetAsync(gmax, 0, ((size_t)2 * GG + (size_t)GG * 64) * sizeof(float), stream);

    k0_prep<<<(64 * 1040 + 255) / 256, 256, 0, stream>>>(W_e2, b_e2, W2T);
    k1_mfma<<<(EE + 255) / 256, 256, 0, stream>>>(x, ei, ea, W_e1, b_e1, W2T, agg, cnt);
    k2_node<<<NN / 4, 256, 0, stream>>>(x, root, conv_b, cnt, agg, Wg, bg, gate);
    k3a_max<<<(NN + 255) / 256, 256, 0, stream>>>(gate, batch, gmax);
    k3b_acc<<<NN / 4, 256, 0, stream>>>(gate, batch, agg, gmax, denom, gctx);
    k3c_norm<<<GG * 64 / 256, 256, 0, stream>>>(gctx, denom);

    float* out_np   = (float*)d_out;
    float* out_stop = out_np + (size_t)NN * CC;
    k4_out<<<NN / 4, 256, 0, stream>>>(agg, gctx, batch, pocket,
                                       W_fc1, b_fc1, W_np, b_np, W_sp, b_sp,
                                       out_np, out_stop);
}

// Round 3
// 552.955 us; speedup vs baseline: 3.4669x; 1.2316x over previous
//
#include <hip/hip_runtime.h>
#include <hip/hip_bf16.h>
#include <math.h>

#define NN 150000
#define EE 600000
#define GG 5000
#define NI 16
#define EI 8
#define GFD 32
#define HH 64
#define CC 40

#define W2ROW 1056   // 64 chunks*16 + bias chunk 16 + 16 zero pad (branch-free prefetch)

typedef __attribute__((ext_vector_type(8))) short short8v;
typedef __attribute__((ext_vector_type(16))) float f32x16;

__device__ __forceinline__ unsigned short f2bf(float f) {
    __hip_bfloat16 h = __float2bfloat16(f);
    return __builtin_bit_cast(unsigned short, h);
}
__device__ __forceinline__ float bf2f(unsigned short u) {
    return __uint_as_float(((unsigned)u) << 16);
}

// ---------------- K0: prep W2T bf16 [64][W2ROW]: W2T[h][k*16+i]=W_e2[k][i*64+h], chunk64=b_e2, pad=0 ----
__global__ void k0_prep(const float* __restrict__ W_e2, const float* __restrict__ b_e2,
                        unsigned short* __restrict__ W2T)
{
    int idx = blockIdx.x * 256 + threadIdx.x;
    if (idx >= 64 * W2ROW) return;
    int h = idx / W2ROW, j = idx % W2ROW;
    float v = 0.f;
    if (j < 1024)      { int k = j >> 4, i = j & 15; v = W_e2[k * 1024 + i * 64 + h]; }
    else if (j < 1040) { int i = j - 1024;           v = b_e2[i * 64 + h]; }
    W2T[idx] = f2bf(v);
}

// ---------------- K1: fused edge MLP + MFMA z-GEMM + scatter ----------------
__device__ __forceinline__ void mfma_step(
    const unsigned short (&sEHT)[65][256], int c, int pf,
    const unsigned short* __restrict__ Bq0, const unsigned short* __restrict__ Bq1,
    int mb, int mr, const float (&xs0)[8], const float (&xs1)[8],
    short8v& curb0, short8v& curb1,
    f32x16& acc00, f32x16& acc01, f32x16& acc10, f32x16& acc11)
{
    short8v n0 = *(const short8v*)(Bq0 + pf * 16);
    short8v n1 = *(const short8v*)(Bq1 + pf * 16);
    int cc = (c & 31) << 1;
    float eh0 = bf2f(sEHT[c][(mb + mr) ^ cc]);
    float eh1 = bf2f(sEHT[c][(mb + 32 + mr) ^ cc]);
    short8v a0, a1;
    #pragma unroll
    for (int q = 0; q < 8; ++q) {
        a0[q] = (short)f2bf(eh0 * xs0[q]);
        a1[q] = (short)f2bf(eh1 * xs1[q]);
    }
    __builtin_amdgcn_s_setprio(1);
    acc00 = __builtin_amdgcn_mfma_f32_32x32x16_bf16(a0, curb0, acc00, 0, 0, 0);
    acc01 = __builtin_amdgcn_mfma_f32_32x32x16_bf16(a0, curb1, acc01, 0, 0, 0);
    acc10 = __builtin_amdgcn_mfma_f32_32x32x16_bf16(a1, curb0, acc10, 0, 0, 0);
    acc11 = __builtin_amdgcn_mfma_f32_32x32x16_bf16(a1, curb1, acc11, 0, 0, 0);
    __builtin_amdgcn_s_setprio(0);
    curb0 = n0; curb1 = n1;
}

__global__ __launch_bounds__(256, 4) void k1_mfma(
    const float* __restrict__ x, const int* __restrict__ ei,
    const float* __restrict__ ea,
    const float* __restrict__ W_e1, const float* __restrict__ b_e1,
    const unsigned short* __restrict__ W2T,
    float* __restrict__ agg, float* __restrict__ cnt)
{
    __shared__ unsigned short sEHT[65][256];   // [k][e ^ ((k&31)<<1)]  bf16; row 64 = 1.0
    __shared__ int sDst[256];

    const int t = threadIdx.x;
    const long long eb = (long long)blockIdx.x * 256;

    // ---- dst + cnt ----
    {
        long long ge = eb + t;
        if (ge < EE) {
            int d = ei[EE + ge];
            sDst[t] = d;
            atomicAdd(&cnt[d], 1.0f);
        } else {
            sDst[t] = -1;
        }
        // bias row: eh = 1.0
        sEHT[64][t] = (unsigned short)0x3F80;
    }
    // ---- edge MLP layer 1 -> sEHT (transposed, swizzled) ----
    {
        const int k = t & 63;
        const int w = t >> 6;
        float w1[8];
        float b1 = b_e1[k];
        #pragma unroll
        for (int j = 0; j < 8; ++j) w1[j] = W_e1[j * 64 + k];
        #pragma unroll 4
        for (int r = 0; r < 64; ++r) {
            int e = w * 64 + r;
            long long ge = eb + e;
            float v = 0.f;
            if (ge < EE) {
                const float4* eap = (const float4*)(ea + ge * EI);
                float4 u0 = eap[0], u1 = eap[1];
                v = b1;
                v = fmaf(u0.x, w1[0], v); v = fmaf(u0.y, w1[1], v);
                v = fmaf(u0.z, w1[2], v); v = fmaf(u0.w, w1[3], v);
                v = fmaf(u1.x, w1[4], v); v = fmaf(u1.y, w1[5], v);
                v = fmaf(u1.z, w1[6], v); v = fmaf(u1.w, w1[7], v);
                v = fmaxf(v, 0.f);
            }
            sEHT[k][e ^ ((k & 31) << 1)] = f2bf(v);
        }
    }

    // ---- per-lane xs gather (no LDS) ----
    const int lane = t & 63;
    const int w = t >> 6;
    const int mr = lane & 31;
    const int half = lane >> 5;
    const int mb = w * 64;

    float xs0[8], xs1[8];
    {
        long long e0 = eb + mb + mr;
        long long e1 = eb + mb + 32 + mr;
        if (e0 < EE) {
            int s0 = ei[e0];
            const float4* xp = (const float4*)(x + (size_t)s0 * NI + half * 8);
            float4 u0 = xp[0], u1 = xp[1];
            xs0[0]=u0.x; xs0[1]=u0.y; xs0[2]=u0.z; xs0[3]=u0.w;
            xs0[4]=u1.x; xs0[5]=u1.y; xs0[6]=u1.z; xs0[7]=u1.w;
        } else {
            #pragma unroll
            for (int q = 0; q < 8; ++q) xs0[q] = 0.f;
        }
        if (e1 < EE) {
            int s1 = ei[e1];
            const float4* xp = (const float4*)(x + (size_t)s1 * NI + half * 8);
            float4 u0 = xp[0], u1 = xp[1];
            xs1[0]=u0.x; xs1[1]=u0.y; xs1[2]=u0.z; xs1[3]=u0.w;
            xs1[4]=u1.x; xs1[5]=u1.y; xs1[6]=u1.z; xs1[7]=u1.w;
        } else {
            #pragma unroll
            for (int q = 0; q < 8; ++q) xs1[q] = 0.f;
        }
    }
    __syncthreads();

    f32x16 acc00, acc01, acc10, acc11;
    #pragma unroll
    for (int r = 0; r < 16; ++r) { acc00[r] = 0.f; acc01[r] = 0.f; acc10[r] = 0.f; acc11[r] = 0.f; }

    const unsigned short* Bq0 = W2T + (size_t)mr * W2ROW + half * 8;
    const unsigned short* Bq1 = Bq0 + 32 * W2ROW;

    short8v bA0 = *(const short8v*)(Bq0);
    short8v bA1 = *(const short8v*)(Bq1);
    short8v bB0 = *(const short8v*)(Bq0 + 16);
    short8v bB1 = *(const short8v*)(Bq1 + 16);

    #pragma unroll 1
    for (int c = 0; c < 64; c += 2) {
        mfma_step(sEHT, c,     c + 2, Bq0, Bq1, mb, mr, xs0, xs1, bA0, bA1, acc00, acc01, acc10, acc11);
        mfma_step(sEHT, c + 1, c + 3, Bq0, Bq1, mb, mr, xs0, xs1, bB0, bB1, acc00, acc01, acc10, acc11);
    }
    // final: bias chunk c=64 (bA holds chunk 64, prefetched at c=62)
    mfma_step(sEHT, 64, 64, Bq0, Bq1, mb, mr, xs0, xs1, bA0, bA1, acc00, acc01, acc10, acc11);

    // ---- epilogue: scatter via atomics (C layout: col=lane&31, row=(r&3)+8*(r>>2)+4*half) ----
    #pragma unroll
    for (int r = 0; r < 16; ++r) {
        int row = (r & 3) + 8 * (r >> 2) + 4 * half;
        int m0 = mb + row;
        int m1 = mb + 32 + row;
        int d0 = sDst[m0];
        int d1 = sDst[m1];
        if (d0 >= 0) {
            atomicAdd(&agg[(size_t)d0 * 64 + mr],      acc00[r]);
            atomicAdd(&agg[(size_t)d0 * 64 + 32 + mr], acc01[r]);
        }
        if (d1 >= 0) {
            atomicAdd(&agg[(size_t)d1 * 64 + mr],      acc10[r]);
            atomicAdd(&agg[(size_t)d1 * 64 + 32 + mr], acc11[r]);
        }
    }
}

// ---------------- K2: mean + root + relu (in place over agg) + gate ----------------
__global__ __launch_bounds__(256) void k2_node(
    const float* __restrict__ x, const float* __restrict__ root,
    const float* __restrict__ conv_bias, const float* __restrict__ cnt,
    float* __restrict__ hn,
    const float* __restrict__ Wg, const float* __restrict__ bg,
    float* __restrict__ gate)
{
    int t = threadIdx.x;
    int n = blockIdx.x * 4 + (t >> 6);
    int h = t & 63;
    float inv = 1.0f / fmaxf(cnt[n], 1.0f);
    float v = hn[(size_t)n * 64 + h] * inv + conv_bias[h];
    const float* xp = x + (size_t)n * NI;
    #pragma unroll
    for (int i = 0; i < NI; ++i) v += xp[i] * root[i * 64 + h];
    v = fmaxf(v, 0.f);
    hn[(size_t)n * 64 + h] = v;
    float gv = v * Wg[h];
    #pragma unroll
    for (int off = 32; off; off >>= 1) gv += __shfl_xor(gv, off);
    if (h == 0) gate[n] = gv + bg[0];
}

// ---------------- K3: per-graph attention pooling (sorted batch; no atomics) ----------------
__device__ __forceinline__ int lbound(const int* __restrict__ b, int v) {
    int lo = 0, hi = NN;
    while (lo < hi) { int mid = (lo + hi) >> 1; if (b[mid] < v) lo = mid + 1; else hi = mid; }
    return lo;
}

__global__ __launch_bounds__(64) void k3_pool(
    const float* __restrict__ gate, const int* __restrict__ batch,
    const float* __restrict__ hn, float* __restrict__ gctx)
{
    int g = blockIdx.x;
    int lane = threadIdx.x;
    int s = lbound(batch, g);
    int e = lbound(batch, g + 1);
    if (e <= s) { gctx[(size_t)g * 64 + lane] = 0.f; return; }

    // pass 1: max (strided lanes + shfl reduce)
    float m = -INFINITY;
    for (int n = s + lane; n < e; n += 64) m = fmaxf(m, gate[n]);
    #pragma unroll
    for (int off = 32; off; off >>= 1) m = fmaxf(m, __shfl_xor(m, off));

    // pass 2: exp-weighted sum (lane owns channel `lane`)
    float acc = 0.f, den = 0.f;
    for (int n = s; n < e; ++n) {
        float ev = expf(gate[n] - m);
        den += ev;
        acc += ev * hn[(size_t)n * 64 + lane];
    }
    gctx[(size_t)g * 64 + lane] = acc / den;
}

// ---------------- K4: FC head + log_softmax + stop ----------------
__global__ __launch_bounds__(256) void k4_out(
    const float* __restrict__ hn, const float* __restrict__ gctx,
    const int* __restrict__ batch, const float* __restrict__ pocket,
    const float* __restrict__ W_fc1, const float* __restrict__ b_fc1,
    const float* __restrict__ W_np, const float* __restrict__ b_np,
    const float* __restrict__ W_sp, const float* __restrict__ b_sp,
    float* __restrict__ out_np, float* __restrict__ out_stop)
{
    __shared__ float sF[4][160];
    __shared__ float sf2[4][64];
    int t = threadIdx.x;
    int nd = t >> 6;
    int h = t & 63;
    int n = blockIdx.x * 4 + nd;
    int g = batch[n];
    float hv = hn[(size_t)n * 64 + h];
    float gc = gctx[(size_t)g * 64 + h];
    sF[nd][h] = hv;
    sF[nd][64 + h] = gc;
    if (h < GFD) sF[nd][128 + h] = pocket[(size_t)g * GFD + h];
    __syncthreads();

    float f = b_fc1[h];
    #pragma unroll 8
    for (int j = 0; j < 160; ++j) f += sF[nd][j] * W_fc1[j * 64 + h];
    f = fmaxf(f, 0.f);
    sf2[nd][h] = f;

    float sv = gc * W_sp[h];
    #pragma unroll
    for (int off = 32; off; off >>= 1) sv += __shfl_xor(sv, off);
    __syncthreads();

    float logit = -INFINITY;
    if (h < CC) {
        logit = b_np[h];
        #pragma unroll 8
        for (int k = 0; k < 64; ++k) logit += sf2[nd][k] * W_np[k * CC + h];
    }
    float mx = logit;
    #pragma unroll
    for (int off = 32; off; off >>= 1) mx = fmaxf(mx, __shfl_xor(mx, off));
    float ex = (h < CC) ? expf(logit - mx) : 0.f;
    float s = ex;
    #pragma unroll
    for (int off = 32; off; off >>= 1) s += __shfl_xor(s, off);
    if (h < CC) out_np[(size_t)n * CC + h] = logit - mx - logf(s);
    if (h == 0) out_stop[n] = 1.f / (1.f + expf(-(sv + b_sp[0])));
}

extern "C" void kernel_launch(void* const* d_in, const int* in_sizes, int n_in,
                              void* d_out, int out_size, void* d_ws, size_t ws_size,
                              hipStream_t stream)
{
    (void)in_sizes; (void)n_in; (void)out_size; (void)ws_size;
    const float* x        = (const float*)d_in[0];
    const int*   ei       = (const int*)d_in[1];
    const float* ea       = (const float*)d_in[2];
    const int*   batch    = (const int*)d_in[3];
    const float* pocket   = (const float*)d_in[4];
    const float* W_e1     = (const float*)d_in[5];
    const float* b_e1     = (const float*)d_in[6];
    const float* W_e2     = (const float*)d_in[7];
    const float* b_e2     = (const float*)d_in[8];
    const float* root     = (const float*)d_in[9];
    const float* conv_b   = (const float*)d_in[10];
    const float* Wg       = (const float*)d_in[11];
    const float* bg       = (const float*)d_in[12];
    const float* W_fc1    = (const float*)d_in[13];
    const float* b_fc1    = (const float*)d_in[14];
    const float* W_np     = (const float*)d_in[15];
    const float* b_np     = (const float*)d_in[16];
    const float* W_sp     = (const float*)d_in[17];
    const float* b_sp     = (const float*)d_in[18];

    float* ws = (float*)d_ws;
    float*    agg   = ws;                           // N*64
    float*    cnt   = agg + (size_t)NN * 64;        // N
    float*    gate  = cnt + NN;                     // N
    float*    gctx  = gate + NN;                    // G*64
    unsigned short* W2T = (unsigned short*)(gctx + (size_t)GG * 64); // 64*W2ROW bf16

    hipMemsetAsync(agg, 0, ((size_t)NN * 64 + NN) * sizeof(float), stream);

    k0_prep<<<(64 * W2ROW + 255) / 256, 256, 0, stream>>>(W_e2, b_e2, W2T);
    k1_mfma<<<(EE + 255) / 256, 256, 0, stream>>>(x, ei, ea, W_e1, b_e1, W2T, agg, cnt);
    k2_node<<<NN / 4, 256, 0, stream>>>(x, root, conv_b, cnt, agg, Wg, bg, gate);
    k3_pool<<<GG, 64, 0, stream>>>(gate, batch, agg, gctx);

    float* out_np   = (float*)d_out;
    float* out_stop = out_np + (size_t)NN * CC;
    k4_out<<<NN / 4, 256, 0, stream>>>(agg, gctx, batch, pocket,
                                       W_fc1, b_fc1, W_np, b_np, W_sp, b_sp,
                                       out_np, out_stop);
}

// Round 4
// 356.568 us; speedup vs baseline: 5.3764x; 1.5508x over previous
//
#include <hip/hip_runtime.h>
#include <hip/hip_bf16.h>
#include <math.h>

#define NN 150000
#define EE 600000
#define GG 5000
#define NI 16
#define EI 8
#define GFD 32
#define HH 64
#define CC 40

#define W2ROW 1056
#define FPAD 68

typedef __attribute__((ext_vector_type(8))) short short8v;
typedef __attribute__((ext_vector_type(16))) float f32x16;

__device__ __forceinline__ unsigned short f2bf(float f) {
    __hip_bfloat16 h = __float2bfloat16(f);
    return __builtin_bit_cast(unsigned short, h);
}
__device__ __forceinline__ float bf2f(unsigned short u) {
    return __uint_as_float(((unsigned)u) << 16);
}

// ---------------- K0: prep bf16 weight views ----------------
__global__ void k0_prep(const float* __restrict__ W_e2, const float* __restrict__ b_e2,
                        const float* __restrict__ W_fc1, const float* __restrict__ W_np,
                        unsigned short* __restrict__ W2T,
                        unsigned short* __restrict__ W1aT,
                        unsigned short* __restrict__ W_npT)
{
    int idx = blockIdx.x * 256 + threadIdx.x;
    if (idx < 64 * W2ROW) {
        int h = idx / W2ROW, j = idx % W2ROW;
        float v = 0.f;
        if (j < 1024)      { int k = j >> 4, i = j & 15; v = W_e2[k * 1024 + i * 64 + h]; }
        else if (j < 1040) { int i = j - 1024;           v = b_e2[i * 64 + h]; }
        W2T[idx] = f2bf(v);
    } else if (idx < 64 * W2ROW + 4096) {
        int i = idx - 64 * W2ROW;
        int h = i >> 6, k = i & 63;
        W1aT[i] = f2bf(W_fc1[k * 64 + h]);
    } else if (idx < 64 * W2ROW + 8192) {
        int i = idx - 64 * W2ROW - 4096;
        int c = i >> 6, h = i & 63;
        W_npT[i] = f2bf(c < CC ? W_np[h * CC + c] : 0.f);
    }
}

// ---------------- K1: fused edge MLP + MFMA z-GEMM + scatter ----------------
__device__ __forceinline__ void mfma_step(
    const unsigned short (&sEHT)[65][256], int c, int pf,
    const unsigned short* __restrict__ Bq0, const unsigned short* __restrict__ Bq1,
    int mb, int mr, const float (&xs0)[8], const float (&xs1)[8],
    short8v& curb0, short8v& curb1,
    f32x16& acc00, f32x16& acc01, f32x16& acc10, f32x16& acc11)
{
    short8v n0 = *(const short8v*)(Bq0 + pf * 16);
    short8v n1 = *(const short8v*)(Bq1 + pf * 16);
    int cc = (c & 31) << 1;
    float eh0 = bf2f(sEHT[c][(mb + mr) ^ cc]);
    float eh1 = bf2f(sEHT[c][(mb + 32 + mr) ^ cc]);
    short8v a0, a1;
    #pragma unroll
    for (int q = 0; q < 8; ++q) {
        a0[q] = (short)f2bf(eh0 * xs0[q]);
        a1[q] = (short)f2bf(eh1 * xs1[q]);
    }
    __builtin_amdgcn_s_setprio(1);
    acc00 = __builtin_amdgcn_mfma_f32_32x32x16_bf16(a0, curb0, acc00, 0, 0, 0);
    acc01 = __builtin_amdgcn_mfma_f32_32x32x16_bf16(a0, curb1, acc01, 0, 0, 0);
    acc10 = __builtin_amdgcn_mfma_f32_32x32x16_bf16(a1, curb0, acc10, 0, 0, 0);
    acc11 = __builtin_amdgcn_mfma_f32_32x32x16_bf16(a1, curb1, acc11, 0, 0, 0);
    __builtin_amdgcn_s_setprio(0);
    curb0 = n0; curb1 = n1;
}

__global__ __launch_bounds__(256, 4) void k1_mfma(
    const float* __restrict__ x, const int* __restrict__ ei,
    const float* __restrict__ ea,
    const float* __restrict__ W_e1, const float* __restrict__ b_e1,
    const unsigned short* __restrict__ W2T,
    float* __restrict__ agg, float* __restrict__ cnt)
{
    __shared__ unsigned short sEHT[65][256];
    __shared__ int sDst[256];

    const int t = threadIdx.x;
    const long long eb = (long long)blockIdx.x * 256;

    {
        long long ge = eb + t;
        if (ge < EE) {
            int d = ei[EE + ge];
            sDst[t] = d;
            atomicAdd(&cnt[d], 1.0f);
        } else {
            sDst[t] = -1;
        }
        sEHT[64][t] = (unsigned short)0x3F80;
    }
    {
        const int k = t & 63;
        const int w = t >> 6;
        float w1[8];
        float b1 = b_e1[k];
        #pragma unroll
        for (int j = 0; j < 8; ++j) w1[j] = W_e1[j * 64 + k];
        #pragma unroll 4
        for (int r = 0; r < 64; ++r) {
            int e = w * 64 + r;
            long long ge = eb + e;
            float v = 0.f;
            if (ge < EE) {
                const float4* eap = (const float4*)(ea + ge * EI);
                float4 u0 = eap[0], u1 = eap[1];
                v = b1;
                v = fmaf(u0.x, w1[0], v); v = fmaf(u0.y, w1[1], v);
                v = fmaf(u0.z, w1[2], v); v = fmaf(u0.w, w1[3], v);
                v = fmaf(u1.x, w1[4], v); v = fmaf(u1.y, w1[5], v);
                v = fmaf(u1.z, w1[6], v); v = fmaf(u1.w, w1[7], v);
                v = fmaxf(v, 0.f);
            }
            sEHT[k][e ^ ((k & 31) << 1)] = f2bf(v);
        }
    }

    const int lane = t & 63;
    const int w = t >> 6;
    const int mr = lane & 31;
    const int half = lane >> 5;
    const int mb = w * 64;

    float xs0[8], xs1[8];
    {
        long long e0 = eb + mb + mr;
        long long e1 = eb + mb + 32 + mr;
        if (e0 < EE) {
            int s0 = ei[e0];
            const float4* xp = (const float4*)(x + (size_t)s0 * NI + half * 8);
            float4 u0 = xp[0], u1 = xp[1];
            xs0[0]=u0.x; xs0[1]=u0.y; xs0[2]=u0.z; xs0[3]=u0.w;
            xs0[4]=u1.x; xs0[5]=u1.y; xs0[6]=u1.z; xs0[7]=u1.w;
        } else {
            #pragma unroll
            for (int q = 0; q < 8; ++q) xs0[q] = 0.f;
        }
        if (e1 < EE) {
            int s1 = ei[e1];
            const float4* xp = (const float4*)(x + (size_t)s1 * NI + half * 8);
            float4 u0 = xp[0], u1 = xp[1];
            xs1[0]=u0.x; xs1[1]=u0.y; xs1[2]=u0.z; xs1[3]=u0.w;
            xs1[4]=u1.x; xs1[5]=u1.y; xs1[6]=u1.z; xs1[7]=u1.w;
        } else {
            #pragma unroll
            for (int q = 0; q < 8; ++q) xs1[q] = 0.f;
        }
    }
    __syncthreads();

    f32x16 acc00, acc01, acc10, acc11;
    #pragma unroll
    for (int r = 0; r < 16; ++r) { acc00[r] = 0.f; acc01[r] = 0.f; acc10[r] = 0.f; acc11[r] = 0.f; }

    const unsigned short* Bq0 = W2T + (size_t)mr * W2ROW + half * 8;
    const unsigned short* Bq1 = Bq0 + 32 * W2ROW;

    short8v bA0 = *(const short8v*)(Bq0);
    short8v bA1 = *(const short8v*)(Bq1);
    short8v bB0 = *(const short8v*)(Bq0 + 16);
    short8v bB1 = *(const short8v*)(Bq1 + 16);

    #pragma unroll 1
    for (int c = 0; c < 64; c += 2) {
        mfma_step(sEHT, c,     c + 2, Bq0, Bq1, mb, mr, xs0, xs1, bA0, bA1, acc00, acc01, acc10, acc11);
        mfma_step(sEHT, c + 1, c + 3, Bq0, Bq1, mb, mr, xs0, xs1, bB0, bB1, acc00, acc01, acc10, acc11);
    }
    mfma_step(sEHT, 64, 64, Bq0, Bq1, mb, mr, xs0, xs1, bA0, bA1, acc00, acc01, acc10, acc11);

    #pragma unroll
    for (int r = 0; r < 16; ++r) {
        int row = (r & 3) + 8 * (r >> 2) + 4 * half;
        int m0 = mb + row;
        int m1 = mb + 32 + row;
        int d0 = sDst[m0];
        int d1 = sDst[m1];
        if (d0 >= 0) {
            atomicAdd(&agg[(size_t)d0 * 64 + mr],      acc00[r]);
            atomicAdd(&agg[(size_t)d0 * 64 + 32 + mr], acc01[r]);
        }
        if (d1 >= 0) {
            atomicAdd(&agg[(size_t)d1 * 64 + mr],      acc10[r]);
            atomicAdd(&agg[(size_t)d1 * 64 + 32 + mr], acc11[r]);
        }
    }
}

// ---------------- K2: mean + root + relu (in place over agg) + gate ----------------
__global__ __launch_bounds__(256) void k2_node(
    const float* __restrict__ x, const float* __restrict__ root,
    const float* __restrict__ conv_bias, const float* __restrict__ cnt,
    float* __restrict__ hn,
    const float* __restrict__ Wg, const float* __restrict__ bg,
    float* __restrict__ gate)
{
    int t = threadIdx.x;
    int n = blockIdx.x * 4 + (t >> 6);
    int h = t & 63;
    float inv = 1.0f / fmaxf(cnt[n], 1.0f);
    float v = hn[(size_t)n * 64 + h] * inv + conv_bias[h];
    const float* xp = x + (size_t)n * NI;
    #pragma unroll
    for (int i = 0; i < NI; ++i) v += xp[i] * root[i * 64 + h];
    v = fmaxf(v, 0.f);
    hn[(size_t)n * 64 + h] = v;
    float gv = v * Wg[h];
    #pragma unroll
    for (int off = 32; off; off >>= 1) gv += __shfl_xor(gv, off);
    if (h == 0) gate[n] = gv + bg[0];
}

// ---------------- K3: per-graph pooling + pg/sg precompute ----------------
__device__ __forceinline__ int lbound(const int* __restrict__ b, int v) {
    int lo = 0, hi = NN;
    while (lo < hi) { int mid = (lo + hi) >> 1; if (b[mid] < v) lo = mid + 1; else hi = mid; }
    return lo;
}

__global__ __launch_bounds__(64) void k3_pool(
    const float* __restrict__ gate, const int* __restrict__ batch,
    const float* __restrict__ hn, const float* __restrict__ pocket,
    const float* __restrict__ W_fc1, const float* __restrict__ b_fc1,
    const float* __restrict__ W_sp, const float* __restrict__ b_sp,
    float* __restrict__ pg, float* __restrict__ sg)
{
    int g = blockIdx.x;
    int lane = threadIdx.x;
    int s = lbound(batch, g);
    int e = lbound(batch, g + 1);

    float gcv = 0.f;
    if (e > s) {
        float m = -INFINITY;
        for (int n = s + lane; n < e; n += 64) m = fmaxf(m, gate[n]);
        #pragma unroll
        for (int off = 32; off; off >>= 1) m = fmaxf(m, __shfl_xor(m, off));
        float acc = 0.f, den = 0.f;
        for (int n = s; n < e; ++n) {
            float ev = expf(gate[n] - m);
            den += ev;
            acc += ev * hn[(size_t)n * 64 + lane];
        }
        gcv = acc / den;
    }

    float sv = gcv * W_sp[lane];
    #pragma unroll
    for (int off = 32; off; off >>= 1) sv += __shfl_xor(sv, off);
    if (lane == 0) sg[g] = 1.f / (1.f + expf(-(sv + b_sp[0])));

    float pk = (lane < GFD) ? pocket[(size_t)g * GFD + lane] : 0.f;
    float pgv = b_fc1[lane];
    #pragma unroll 8
    for (int k = 0; k < 64; ++k)
        pgv = fmaf(__shfl(gcv, k), W_fc1[(64 + k) * 64 + lane], pgv);
    #pragma unroll 8
    for (int k = 0; k < 32; ++k)
        pgv = fmaf(__shfl(pk, k), W_fc1[(128 + k) * 64 + lane], pgv);
    pg[(size_t)g * 64 + lane] = pgv;
}

// ---------------- K4: MFMA head ----------------
__global__ __launch_bounds__(256, 4) void k4_mfma(
    const float* __restrict__ hn, const int* __restrict__ batch,
    const float* __restrict__ pg, const float* __restrict__ sg,
    const unsigned short* __restrict__ W1aT, const unsigned short* __restrict__ W_npT,
    const float* __restrict__ b_np,
    float* __restrict__ out_np, float* __restrict__ out_stop)
{
    __shared__ __align__(16) float sF[4][32][FPAD];
    __shared__ int sB[128];

    const int t = threadIdx.x;
    const int wv = t >> 6, lane = t & 63;
    const int mr = lane & 31, half = lane >> 5;
    const int nb = blockIdx.x * 128;

    if (t < 128) {
        int n = nb + t;
        sB[t] = (n < NN) ? batch[n] : 0;
    }

    const int node = nb + wv * 32 + mr;

    f32x16 acc0, acc1;
    #pragma unroll
    for (int r = 0; r < 16; ++r) { acc0[r] = 0.f; acc1[r] = 0.f; }

    #pragma unroll
    for (int c = 0; c < 4; ++c) {
        short8v a;
        if (node < NN) {
            const float4* hp = (const float4*)(hn + (size_t)node * 64 + c * 16 + half * 8);
            float4 u0 = hp[0], u1 = hp[1];
            a[0] = (short)f2bf(u0.x); a[1] = (short)f2bf(u0.y);
            a[2] = (short)f2bf(u0.z); a[3] = (short)f2bf(u0.w);
            a[4] = (short)f2bf(u1.x); a[5] = (short)f2bf(u1.y);
            a[6] = (short)f2bf(u1.z); a[7] = (short)f2bf(u1.w);
        } else {
            #pragma unroll
            for (int q = 0; q < 8; ++q) a[q] = 0;
        }
        short8v b0 = *(const short8v*)(W1aT + (size_t)mr * 64        + c * 16 + half * 8);
        short8v b1 = *(const short8v*)(W1aT + (size_t)(mr + 32) * 64 + c * 16 + half * 8);
        acc0 = __builtin_amdgcn_mfma_f32_32x32x16_bf16(a, b0, acc0, 0, 0, 0);
        acc1 = __builtin_amdgcn_mfma_f32_32x32x16_bf16(a, b1, acc1, 0, 0, 0);
    }
    __syncthreads();

    #pragma unroll
    for (int r = 0; r < 16; ++r) {
        int row = (r & 3) + 8 * (r >> 2) + 4 * half;
        int g = sB[wv * 32 + row];
        float p0 = pg[(size_t)g * 64 + mr];
        float p1 = pg[(size_t)g * 64 + 32 + mr];
        sF[wv][row][mr]      = fmaxf(acc0[r] + p0, 0.f);
        sF[wv][row][32 + mr] = fmaxf(acc1[r] + p1, 0.f);
    }

    f32x16 acc2, acc3;
    #pragma unroll
    for (int r = 0; r < 16; ++r) { acc2[r] = 0.f; acc3[r] = 0.f; }

    #pragma unroll
    for (int c = 0; c < 4; ++c) {
        const float* fp = &sF[wv][mr][c * 16 + half * 8];
        float4 u0 = *(const float4*)(fp);
        float4 u1 = *(const float4*)(fp + 4);
        short8v a;
        a[0] = (short)f2bf(u0.x); a[1] = (short)f2bf(u0.y);
        a[2] = (short)f2bf(u0.z); a[3] = (short)f2bf(u0.w);
        a[4] = (short)f2bf(u1.x); a[5] = (short)f2bf(u1.y);
        a[6] = (short)f2bf(u1.z); a[7] = (short)f2bf(u1.w);
        short8v b0 = *(const short8v*)(W_npT + (size_t)mr * 64        + c * 16 + half * 8);
        short8v b1 = *(const short8v*)(W_npT + (size_t)(mr + 32) * 64 + c * 16 + half * 8);
        acc2 = __builtin_amdgcn_mfma_f32_32x32x16_bf16(a, b0, acc2, 0, 0, 0);
        acc3 = __builtin_amdgcn_mfma_f32_32x32x16_bf16(a, b1, acc3, 0, 0, 0);
    }

    float bn1 = b_np[mr];
    float bn2 = (mr < 8) ? b_np[32 + mr] : 0.f;

    #pragma unroll
    for (int r = 0; r < 16; ++r) {
        int row = (r & 3) + 8 * (r >> 2) + 4 * half;
        int n = nb + wv * 32 + row;
        float v1 = acc2[r] + bn1;
        float v2 = acc3[r] + bn2;
        float m = (mr < 8) ? fmaxf(v1, v2) : v1;
        #pragma unroll
        for (int off = 16; off; off >>= 1) m = fmaxf(m, __shfl_xor(m, off));
        float s = expf(v1 - m) + ((mr < 8) ? expf(v2 - m) : 0.f);
        #pragma unroll
        for (int off = 16; off; off >>= 1) s += __shfl_xor(s, off);
        float ls = m + logf(s);
        if (n < NN) {
            out_np[(size_t)n * CC + mr] = v1 - ls;
            if (mr < 8) out_np[(size_t)n * CC + 32 + mr] = v2 - ls;
            if (mr == 0) out_stop[n] = sg[sB[wv * 32 + row]];
        }
    }
}

extern "C" void kernel_launch(void* const* d_in, const int* in_sizes, int n_in,
                              void* d_out, int out_size, void* d_ws, size_t ws_size,
                              hipStream_t stream)
{
    (void)in_sizes; (void)n_in; (void)out_size; (void)ws_size;
    const float* x        = (const float*)d_in[0];
    const int*   ei       = (const int*)d_in[1];
    const float* ea       = (const float*)d_in[2];
    const int*   batch    = (const int*)d_in[3];
    const float* pocket   = (const float*)d_in[4];
    const float* W_e1     = (const float*)d_in[5];
    const float* b_e1     = (const float*)d_in[6];
    const float* W_e2     = (const float*)d_in[7];
    const float* b_e2     = (const float*)d_in[8];
    const float* root     = (const float*)d_in[9];
    const float* conv_b   = (const float*)d_in[10];
    const float* Wg       = (const float*)d_in[11];
    const float* bg       = (const float*)d_in[12];
    const float* W_fc1    = (const float*)d_in[13];
    const float* b_fc1    = (const float*)d_in[14];
    const float* W_np     = (const float*)d_in[15];
    const float* b_np     = (const float*)d_in[16];
    const float* W_sp     = (const float*)d_in[17];
    const float* b_sp     = (const float*)d_in[18];

    float* ws = (float*)d_ws;
    float*    agg   = ws;                           // N*64
    float*    cnt   = agg + (size_t)NN * 64;        // N
    float*    gate  = cnt + NN;                     // N
    float*    pg    = gate + NN;                    // G*64
    float*    sg    = pg + (size_t)GG * 64;         // G
    unsigned short* W2T  = (unsigned short*)(sg + GG);
    unsigned short* W1aT = W2T + (size_t)64 * W2ROW;
    unsigned short* W_npT= W1aT + 4096;

    hipMemsetAsync(agg, 0, ((size_t)NN * 64 + NN) * sizeof(float), stream);

    k0_prep<<<(64 * W2ROW + 8192 + 255) / 256, 256, 0, stream>>>(
        W_e2, b_e2, W_fc1, W_np, W2T, W1aT, W_npT);
    k1_mfma<<<(EE + 255) / 256, 256, 0, stream>>>(x, ei, ea, W_e1, b_e1, W2T, agg, cnt);
    k2_node<<<NN / 4, 256, 0, stream>>>(x, root, conv_b, cnt, agg, Wg, bg, gate);
    k3_pool<<<GG, 64, 0, stream>>>(gate, batch, agg, pocket, W_fc1, b_fc1, W_sp, b_sp, pg, sg);

    float* out_np   = (float*)d_out;
    float* out_stop = out_np + (size_t)NN * CC;
    k4_mfma<<<(NN + 127) / 128, 256, 0, stream>>>(agg, batch, pg, sg, W1aT, W_npT, b_np,
                                                  out_np, out_stop);
}

// Round 5
// 355.002 us; speedup vs baseline: 5.4001x; 1.0044x over previous
//
#include <hip/hip_runtime.h>
#include <hip/hip_bf16.h>
#include <math.h>

#define NN 150000
#define EE 600000
#define GG 5000
#define NI 16
#define EI 8
#define GFD 32
#define HH 64
#define CC 40

#define W2ROW 1056
#define FPAD 68

typedef __attribute__((ext_vector_type(8))) short short8v;
typedef __attribute__((ext_vector_type(16))) float f32x16;

__device__ __forceinline__ unsigned short f2bf(float f) {
    __hip_bfloat16 h = __float2bfloat16(f);
    return __builtin_bit_cast(unsigned short, h);
}
__device__ __forceinline__ float bf2f(unsigned short u) {
    return __uint_as_float(((unsigned)u) << 16);
}
// HW packed f32->bf16 convert (gfx950): lo -> [15:0], hi -> [31:16]
__device__ __forceinline__ unsigned cvtpk(float lo, float hi) {
    unsigned r;
    asm("v_cvt_pk_bf16_f32 %0, %1, %2" : "=v"(r) : "v"(lo), "v"(hi));
    return r;
}
// A-fragment: bf16(eh * xs[q]) for q=0..7, via 4x cvt_pk
__device__ __forceinline__ short8v zfrag(float eh, const float (&xs)[8]) {
    union { short8v v; unsigned u[4]; } A;
    #pragma unroll
    for (int q = 0; q < 4; ++q)
        A.u[q] = cvtpk(eh * xs[2 * q], eh * xs[2 * q + 1]);
    return A.v;
}

// ---------------- K0: prep bf16 weight views ----------------
__global__ void k0_prep(const float* __restrict__ W_e2, const float* __restrict__ b_e2,
                        const float* __restrict__ W_fc1, const float* __restrict__ W_np,
                        unsigned short* __restrict__ W2T,
                        unsigned short* __restrict__ W1aT,
                        unsigned short* __restrict__ W_npT)
{
    int idx = blockIdx.x * 256 + threadIdx.x;
    if (idx < 64 * W2ROW) {
        int h = idx / W2ROW, j = idx % W2ROW;
        float v = 0.f;
        if (j < 1024)      { int k = j >> 4, i = j & 15; v = W_e2[k * 1024 + i * 64 + h]; }
        else if (j < 1040) { int i = j - 1024;           v = b_e2[i * 64 + h]; }
        W2T[idx] = f2bf(v);
    } else if (idx < 64 * W2ROW + 4096) {
        int i = idx - 64 * W2ROW;
        int h = i >> 6, k = i & 63;
        W1aT[i] = f2bf(W_fc1[k * 64 + h]);
    } else if (idx < 64 * W2ROW + 8192) {
        int i = idx - 64 * W2ROW - 4096;
        int c = i >> 6, h = i & 63;
        W_npT[i] = f2bf(c < CC ? W_np[h * CC + c] : 0.f);
    }
}

// ---------------- K1: fused edge MLP + MFMA z-GEMM + scatter ----------------
__device__ __forceinline__ void mfma_step(
    const unsigned short (&sEHT)[65][256], int c, int pf,
    const unsigned short* __restrict__ Bq0, const unsigned short* __restrict__ Bq1,
    int mb, int mr, const float (&xs0)[8], const float (&xs1)[8],
    short8v& curb0, short8v& curb1,
    f32x16& acc00, f32x16& acc01, f32x16& acc10, f32x16& acc11)
{
    short8v n0 = *(const short8v*)(Bq0 + pf * 16);
    short8v n1 = *(const short8v*)(Bq1 + pf * 16);
    int cc = (c & 31) << 1;
    float eh0 = bf2f(sEHT[c][(mb + mr) ^ cc]);
    float eh1 = bf2f(sEHT[c][(mb + 32 + mr) ^ cc]);
    short8v a0 = zfrag(eh0, xs0);
    short8v a1 = zfrag(eh1, xs1);
    __builtin_amdgcn_s_setprio(1);
    acc00 = __builtin_amdgcn_mfma_f32_32x32x16_bf16(a0, curb0, acc00, 0, 0, 0);
    acc01 = __builtin_amdgcn_mfma_f32_32x32x16_bf16(a0, curb1, acc01, 0, 0, 0);
    acc10 = __builtin_amdgcn_mfma_f32_32x32x16_bf16(a1, curb0, acc10, 0, 0, 0);
    acc11 = __builtin_amdgcn_mfma_f32_32x32x16_bf16(a1, curb1, acc11, 0, 0, 0);
    __builtin_amdgcn_s_setprio(0);
    curb0 = n0; curb1 = n1;
}

__global__ __launch_bounds__(256, 3) void k1_mfma(
    const float* __restrict__ x, const int* __restrict__ ei,
    const float* __restrict__ ea,
    const float* __restrict__ W_e1, const float* __restrict__ b_e1,
    const unsigned short* __restrict__ W2T,
    float* __restrict__ agg, float* __restrict__ cnt)
{
    __shared__ unsigned short sEHT[65][256];
    __shared__ int sDst[256];

    const int t = threadIdx.x;
    const long long eb = (long long)blockIdx.x * 256;

    {
        long long ge = eb + t;
        if (ge < EE) {
            int d = ei[EE + ge];
            sDst[t] = d;
            atomicAdd(&cnt[d], 1.0f);
        } else {
            sDst[t] = -1;
        }
        sEHT[64][t] = (unsigned short)0x3F80;
    }
    {
        const int k = t & 63;
        const int w = t >> 6;
        float w1[8];
        float b1 = b_e1[k];
        #pragma unroll
        for (int j = 0; j < 8; ++j) w1[j] = W_e1[j * 64 + k];
        #pragma unroll 4
        for (int r = 0; r < 64; ++r) {
            int e = w * 64 + r;
            long long ge = eb + e;
            float v = 0.f;
            if (ge < EE) {
                const float4* eap = (const float4*)(ea + ge * EI);
                float4 u0 = eap[0], u1 = eap[1];
                v = b1;
                v = fmaf(u0.x, w1[0], v); v = fmaf(u0.y, w1[1], v);
                v = fmaf(u0.z, w1[2], v); v = fmaf(u0.w, w1[3], v);
                v = fmaf(u1.x, w1[4], v); v = fmaf(u1.y, w1[5], v);
                v = fmaf(u1.z, w1[6], v); v = fmaf(u1.w, w1[7], v);
                v = fmaxf(v, 0.f);
            }
            sEHT[k][e ^ ((k & 31) << 1)] = f2bf(v);
        }
    }

    const int lane = t & 63;
    const int w = t >> 6;
    const int mr = lane & 31;
    const int half = lane >> 5;
    const int mb = w * 64;

    float xs0[8], xs1[8];
    {
        long long e0 = eb + mb + mr;
        long long e1 = eb + mb + 32 + mr;
        if (e0 < EE) {
            int s0 = ei[e0];
            const float4* xp = (const float4*)(x + (size_t)s0 * NI + half * 8);
            float4 u0 = xp[0], u1 = xp[1];
            xs0[0]=u0.x; xs0[1]=u0.y; xs0[2]=u0.z; xs0[3]=u0.w;
            xs0[4]=u1.x; xs0[5]=u1.y; xs0[6]=u1.z; xs0[7]=u1.w;
        } else {
            #pragma unroll
            for (int q = 0; q < 8; ++q) xs0[q] = 0.f;
        }
        if (e1 < EE) {
            int s1 = ei[e1];
            const float4* xp = (const float4*)(x + (size_t)s1 * NI + half * 8);
            float4 u0 = xp[0], u1 = xp[1];
            xs1[0]=u0.x; xs1[1]=u0.y; xs1[2]=u0.z; xs1[3]=u0.w;
            xs1[4]=u1.x; xs1[5]=u1.y; xs1[6]=u1.z; xs1[7]=u1.w;
        } else {
            #pragma unroll
            for (int q = 0; q < 8; ++q) xs1[q] = 0.f;
        }
    }
    __syncthreads();

    f32x16 acc00, acc01, acc10, acc11;
    #pragma unroll
    for (int r = 0; r < 16; ++r) { acc00[r] = 0.f; acc01[r] = 0.f; acc10[r] = 0.f; acc11[r] = 0.f; }

    const unsigned short* Bq0 = W2T + (size_t)mr * W2ROW + half * 8;
    const unsigned short* Bq1 = Bq0 + 32 * W2ROW;

    short8v bA0 = *(const short8v*)(Bq0);
    short8v bA1 = *(const short8v*)(Bq1);
    short8v bB0 = *(const short8v*)(Bq0 + 16);
    short8v bB1 = *(const short8v*)(Bq1 + 16);

    #pragma unroll 2
    for (int c = 0; c < 64; c += 2) {
        mfma_step(sEHT, c,     c + 2, Bq0, Bq1, mb, mr, xs0, xs1, bA0, bA1, acc00, acc01, acc10, acc11);
        mfma_step(sEHT, c + 1, c + 3, Bq0, Bq1, mb, mr, xs0, xs1, bB0, bB1, acc00, acc01, acc10, acc11);
    }
    mfma_step(sEHT, 64, 64, Bq0, Bq1, mb, mr, xs0, xs1, bA0, bA1, acc00, acc01, acc10, acc11);

    #pragma unroll
    for (int r = 0; r < 16; ++r) {
        int row = (r & 3) + 8 * (r >> 2) + 4 * half;
        int m0 = mb + row;
        int m1 = mb + 32 + row;
        int d0 = sDst[m0];
        int d1 = sDst[m1];
        if (d0 >= 0) {
            atomicAdd(&agg[(size_t)d0 * 64 + mr],      acc00[r]);
            atomicAdd(&agg[(size_t)d0 * 64 + 32 + mr], acc01[r]);
        }
        if (d1 >= 0) {
            atomicAdd(&agg[(size_t)d1 * 64 + mr],      acc10[r]);
            atomicAdd(&agg[(size_t)d1 * 64 + 32 + mr], acc11[r]);
        }
    }
}

// ---------------- K2: mean + root + relu (in place over agg) + gate ----------------
__global__ __launch_bounds__(256) void k2_node(
    const float* __restrict__ x, const float* __restrict__ root,
    const float* __restrict__ conv_bias, const float* __restrict__ cnt,
    float* __restrict__ hn,
    const float* __restrict__ Wg, const float* __restrict__ bg,
    float* __restrict__ gate)
{
    int t = threadIdx.x;
    int n = blockIdx.x * 4 + (t >> 6);
    int h = t & 63;
    float inv = 1.0f / fmaxf(cnt[n], 1.0f);
    float v = hn[(size_t)n * 64 + h] * inv + conv_bias[h];
    const float* xp = x + (size_t)n * NI;
    #pragma unroll
    for (int i = 0; i < NI; ++i) v += xp[i] * root[i * 64 + h];
    v = fmaxf(v, 0.f);
    hn[(size_t)n * 64 + h] = v;
    float gv = v * Wg[h];
    #pragma unroll
    for (int off = 32; off; off >>= 1) gv += __shfl_xor(gv, off);
    if (h == 0) gate[n] = gv + bg[0];
}

// ---------------- K3: per-graph pooling + pg/sg precompute ----------------
__device__ __forceinline__ int lbound(const int* __restrict__ b, int v) {
    int lo = 0, hi = NN;
    while (lo < hi) { int mid = (lo + hi) >> 1; if (b[mid] < v) lo = mid + 1; else hi = mid; }
    return lo;
}

__global__ __launch_bounds__(64) void k3_pool(
    const float* __restrict__ gate, const int* __restrict__ batch,
    const float* __restrict__ hn, const float* __restrict__ pocket,
    const float* __restrict__ W_fc1, const float* __restrict__ b_fc1,
    const float* __restrict__ W_sp, const float* __restrict__ b_sp,
    float* __restrict__ pg, float* __restrict__ sg)
{
    int g = blockIdx.x;
    int lane = threadIdx.x;
    int s = lbound(batch, g);
    int e = lbound(batch, g + 1);

    float gcv = 0.f;
    if (e > s) {
        float m = -INFINITY;
        for (int n = s + lane; n < e; n += 64) m = fmaxf(m, gate[n]);
        #pragma unroll
        for (int off = 32; off; off >>= 1) m = fmaxf(m, __shfl_xor(m, off));
        float acc = 0.f, den = 0.f;
        for (int n = s; n < e; ++n) {
            float ev = expf(gate[n] - m);
            den += ev;
            acc += ev * hn[(size_t)n * 64 + lane];
        }
        gcv = acc / den;
    }

    float sv = gcv * W_sp[lane];
    #pragma unroll
    for (int off = 32; off; off >>= 1) sv += __shfl_xor(sv, off);
    if (lane == 0) sg[g] = 1.f / (1.f + expf(-(sv + b_sp[0])));

    float pk = (lane < GFD) ? pocket[(size_t)g * GFD + lane] : 0.f;
    float pgv = b_fc1[lane];
    #pragma unroll 8
    for (int k = 0; k < 64; ++k)
        pgv = fmaf(__shfl(gcv, k), W_fc1[(64 + k) * 64 + lane], pgv);
    #pragma unroll 8
    for (int k = 0; k < 32; ++k)
        pgv = fmaf(__shfl(pk, k), W_fc1[(128 + k) * 64 + lane], pgv);
    pg[(size_t)g * 64 + lane] = pgv;
}

// ---------------- K4: MFMA head ----------------
__global__ __launch_bounds__(256, 4) void k4_mfma(
    const float* __restrict__ hn, const int* __restrict__ batch,
    const float* __restrict__ pg, const float* __restrict__ sg,
    const unsigned short* __restrict__ W1aT, const unsigned short* __restrict__ W_npT,
    const float* __restrict__ b_np,
    float* __restrict__ out_np, float* __restrict__ out_stop)
{
    __shared__ __align__(16) float sF[4][32][FPAD];
    __shared__ int sB[128];

    const int t = threadIdx.x;
    const int wv = t >> 6, lane = t & 63;
    const int mr = lane & 31, half = lane >> 5;
    const int nb = blockIdx.x * 128;

    if (t < 128) {
        int n = nb + t;
        sB[t] = (n < NN) ? batch[n] : 0;
    }

    const int node = nb + wv * 32 + mr;

    f32x16 acc0, acc1;
    #pragma unroll
    for (int r = 0; r < 16; ++r) { acc0[r] = 0.f; acc1[r] = 0.f; }

    #pragma unroll
    for (int c = 0; c < 4; ++c) {
        short8v a;
        if (node < NN) {
            const float4* hp = (const float4*)(hn + (size_t)node * 64 + c * 16 + half * 8);
            float4 u0 = hp[0], u1 = hp[1];
            union { short8v v; unsigned u[4]; } A;
            A.u[0] = cvtpk(u0.x, u0.y); A.u[1] = cvtpk(u0.z, u0.w);
            A.u[2] = cvtpk(u1.x, u1.y); A.u[3] = cvtpk(u1.z, u1.w);
            a = A.v;
        } else {
            #pragma unroll
            for (int q = 0; q < 8; ++q) a[q] = 0;
        }
        short8v b0 = *(const short8v*)(W1aT + (size_t)mr * 64        + c * 16 + half * 8);
        short8v b1 = *(const short8v*)(W1aT + (size_t)(mr + 32) * 64 + c * 16 + half * 8);
        acc0 = __builtin_amdgcn_mfma_f32_32x32x16_bf16(a, b0, acc0, 0, 0, 0);
        acc1 = __builtin_amdgcn_mfma_f32_32x32x16_bf16(a, b1, acc1, 0, 0, 0);
    }
    __syncthreads();

    #pragma unroll
    for (int r = 0; r < 16; ++r) {
        int row = (r & 3) + 8 * (r >> 2) + 4 * half;
        int g = sB[wv * 32 + row];
        float p0 = pg[(size_t)g * 64 + mr];
        float p1 = pg[(size_t)g * 64 + 32 + mr];
        sF[wv][row][mr]      = fmaxf(acc0[r] + p0, 0.f);
        sF[wv][row][32 + mr] = fmaxf(acc1[r] + p1, 0.f);
    }

    f32x16 acc2, acc3;
    #pragma unroll
    for (int r = 0; r < 16; ++r) { acc2[r] = 0.f; acc3[r] = 0.f; }

    #pragma unroll
    for (int c = 0; c < 4; ++c) {
        const float* fp = &sF[wv][mr][c * 16 + half * 8];
        float4 u0 = *(const float4*)(fp);
        float4 u1 = *(const float4*)(fp + 4);
        union { short8v v; unsigned u[4]; } A;
        A.u[0] = cvtpk(u0.x, u0.y); A.u[1] = cvtpk(u0.z, u0.w);
        A.u[2] = cvtpk(u1.x, u1.y); A.u[3] = cvtpk(u1.z, u1.w);
        short8v a = A.v;
        short8v b0 = *(const short8v*)(W_npT + (size_t)mr * 64        + c * 16 + half * 8);
        short8v b1 = *(const short8v*)(W_npT + (size_t)(mr + 32) * 64 + c * 16 + half * 8);
        acc2 = __builtin_amdgcn_mfma_f32_32x32x16_bf16(a, b0, acc2, 0, 0, 0);
        acc3 = __builtin_amdgcn_mfma_f32_32x32x16_bf16(a, b1, acc3, 0, 0, 0);
    }

    float bn1 = b_np[mr];
    float bn2 = (mr < 8) ? b_np[32 + mr] : 0.f;

    #pragma unroll
    for (int r = 0; r < 16; ++r) {
        int row = (r & 3) + 8 * (r >> 2) + 4 * half;
        int n = nb + wv * 32 + row;
        float v1 = acc2[r] + bn1;
        float v2 = acc3[r] + bn2;
        float m = (mr < 8) ? fmaxf(v1, v2) : v1;
        #pragma unroll
        for (int off = 16; off; off >>= 1) m = fmaxf(m, __shfl_xor(m, off));
        float s = expf(v1 - m) + ((mr < 8) ? expf(v2 - m) : 0.f);
        #pragma unroll
        for (int off = 16; off; off >>= 1) s += __shfl_xor(s, off);
        float ls = m + logf(s);
        if (n < NN) {
            out_np[(size_t)n * CC + mr] = v1 - ls;
            if (mr < 8) out_np[(size_t)n * CC + 32 + mr] = v2 - ls;
            if (mr == 0) out_stop[n] = sg[sB[wv * 32 + row]];
        }
    }
}

extern "C" void kernel_launch(void* const* d_in, const int* in_sizes, int n_in,
                              void* d_out, int out_size, void* d_ws, size_t ws_size,
                              hipStream_t stream)
{
    (void)in_sizes; (void)n_in; (void)out_size; (void)ws_size;
    const float* x        = (const float*)d_in[0];
    const int*   ei       = (const int*)d_in[1];
    const float* ea       = (const float*)d_in[2];
    const int*   batch    = (const int*)d_in[3];
    const float* pocket   = (const float*)d_in[4];
    const float* W_e1     = (const float*)d_in[5];
    const float* b_e1     = (const float*)d_in[6];
    const float* W_e2     = (const float*)d_in[7];
    const float* b_e2     = (const float*)d_in[8];
    const float* root     = (const float*)d_in[9];
    const float* conv_b   = (const float*)d_in[10];
    const float* Wg       = (const float*)d_in[11];
    const float* bg       = (const float*)d_in[12];
    const float* W_fc1    = (const float*)d_in[13];
    const float* b_fc1    = (const float*)d_in[14];
    const float* W_np     = (const float*)d_in[15];
    const float* b_np     = (const float*)d_in[16];
    const float* W_sp     = (const float*)d_in[17];
    const float* b_sp     = (const float*)d_in[18];

    float* ws = (float*)d_ws;
    float*    agg   = ws;                           // N*64
    float*    cnt   = agg + (size_t)NN * 64;        // N
    float*    gate  = cnt + NN;                     // N
    float*    pg    = gate + NN;                    // G*64
    float*    sg    = pg + (size_t)GG * 64;         // G
    unsigned short* W2T  = (unsigned short*)(sg + GG);
    unsigned short* W1aT = W2T + (size_t)64 * W2ROW;
    unsigned short* W_npT= W1aT + 4096;

    hipMemsetAsync(agg, 0, ((size_t)NN * 64 + NN) * sizeof(float), stream);

    k0_prep<<<(64 * W2ROW + 8192 + 255) / 256, 256, 0, stream>>>(
        W_e2, b_e2, W_fc1, W_np, W2T, W1aT, W_npT);
    k1_mfma<<<(EE + 255) / 256, 256, 0, stream>>>(x, ei, ea, W_e1, b_e1, W2T, agg, cnt);
    k2_node<<<NN / 4, 256, 0, stream>>>(x, root, conv_b, cnt, agg, Wg, bg, gate);
    k3_pool<<<GG, 64, 0, stream>>>(gate, batch, agg, pocket, W_fc1, b_fc1, W_sp, b_sp, pg, sg);

    float* out_np   = (float*)d_out;
    float* out_stop = out_np + (size_t)NN * CC;
    k4_mfma<<<(NN + 127) / 128, 256, 0, stream>>>(agg, batch, pg, sg, W1aT, W_npT, b_np,
                                                  out_np, out_stop);
}